// Round 6
// baseline (105.853 us; speedup 1.0000x reference)
//
#include <hip/hip_runtime.h>
#include <math.h>
#include <float.h>

// ChamferLoss via MFMA: set1/set2 [8, 4096, 3] fp32 -> scalar
//
// d^2[m][n] = |q_m|^2 + |p_n|^2 - 2 q_m.p_n computed as ONE
// mfma_f32_32x32x16_bf16 per 32x32 tile, using the K=16 dim to carry:
//   k0-2 : A=-2*q_hi.xyz         B=p_hi.xyz
//   k3-5 : A=-2*q_lo.xyz         B=p_hi.xyz
//   k6-8 : A=-2*q_hi.xyz         B=p_lo.xyz
//   k9-11: A=-2*q_lo.xyz         B=p_lo.xyz
//   k12  : A=1.0                 B=|p|^2_hi
//   k13  : A=1.0                 B=|p|^2_lo
//   k14  : A=|q|^2_hi            B=1.0
//   k15  : A=|q|^2_lo            B=1.0
// => D = full d~^2 tile (hi/lo split residual ~2^-18, fp32 accum).
// Epilogue per element: 1 v_min_f32 into register row-mins.
//
// Verified layouts (learn_hip m74/m101/m89):
//   A: lane holds A[m=lane&31][k=(lane>>5)*8+j], j=0..7 (8 bf16 = uint4)
//   B: lane holds B[k=(lane>>5)*8+j][n=lane&31]
//   C/D: col=lane&31, row=(reg&3)+8*(reg>>2)+4*(lane>>5), reg 0..15

#define BATCH   8
#define NPTS    4096
#define TILES   (NPTS / 32)      // 128 tiles per batch
#define THREADS 256
#define NW      4                // waves per block
#define CHUNK   32               // B-tiles staged per LDS chunk
#define NCHUNK  (TILES / CHUNK)  // 4

typedef __bf16 bf16x8 __attribute__((ext_vector_type(8)));
typedef float  f32x16 __attribute__((ext_vector_type(16)));

static __device__ __forceinline__ unsigned short f2bf(float x) {
    unsigned int u = __float_as_uint(x);
    u += 0x7FFFu + ((u >> 16) & 1u);           // round-to-nearest-even
    return (unsigned short)(u >> 16);
}
static __device__ __forceinline__ float bf2f(unsigned short b) {
    return __uint_as_float(((unsigned int)b) << 16);
}

// ws layout (uint4 units): Afr[2*8*128*64] then Bfr[2*8*128*64]  (2 MB each)
#define FRAGS_PER_SET_PAIR (2 * BATCH * TILES * 64)

__global__ __launch_bounds__(256)
void pack_frags(const float* __restrict__ s1, const float* __restrict__ s2,
                uint4* __restrict__ Afr, uint4* __restrict__ Bfr)
{
    const int t    = blockIdx.x * 256 + threadIdx.x;   // 0..131071
    const int l    = t & 63;
    const int tile = (t >> 6) & (TILES - 1);
    const int b    = (t >> 13) & 7;
    const int set  = t >> 16;

    const float* __restrict__ src = set ? s2 : s1;
    const int pidx = b * NPTS + tile * 32 + (l & 31);
    const float x = src[3 * pidx + 0];
    const float y = src[3 * pidx + 1];
    const float z = src[3 * pidx + 2];

    // hi/lo of -2q (exact x-2 scaling happens before split)
    const float cx = -2.0f * x, cy = -2.0f * y, cz = -2.0f * z;
    const unsigned short cxh = f2bf(cx), cyh = f2bf(cy), czh = f2bf(cz);
    const unsigned short cxl = f2bf(cx - bf2f(cxh));
    const unsigned short cyl = f2bf(cy - bf2f(cyh));
    const unsigned short czl = f2bf(cz - bf2f(czh));
    // hi/lo of p
    const unsigned short pxh = f2bf(x), pyh = f2bf(y), pzh = f2bf(z);
    const unsigned short pxl = f2bf(x - bf2f(pxh));
    const unsigned short pyl = f2bf(y - bf2f(pyh));
    const unsigned short pzl = f2bf(z - bf2f(pzh));
    // hi/lo of |p|^2 (== |q|^2, same point)
    const float n2 = fmaf(x, x, fmaf(y, y, z * z));
    const unsigned short nh = f2bf(n2), nl = f2bf(n2 - bf2f(nh));
    const unsigned short one = 0x3F80;

    unsigned short A[8], B[8];
    if (l < 32) {            // j0..7 <-> k0..7
        A[0] = cxh; A[1] = cyh; A[2] = czh;    // k0-2: -2q_hi
        A[3] = cxl; A[4] = cyl; A[5] = czl;    // k3-5: -2q_lo
        A[6] = cxh; A[7] = cyh;                // k6-7: -2q_hi.xy
        B[0] = pxh; B[1] = pyh; B[2] = pzh;    // k0-2: p_hi
        B[3] = pxh; B[4] = pyh; B[5] = pzh;    // k3-5: p_hi
        B[6] = pxl; B[7] = pyl;                // k6-7: p_lo.xy
    } else {                 // j0..7 <-> k8..15
        A[0] = czh;                            // k8: -2q_hi.z
        A[1] = cxl; A[2] = cyl; A[3] = czl;    // k9-11: -2q_lo
        A[4] = one; A[5] = one;                // k12-13: 1.0
        A[6] = nh;  A[7] = nl;                 // k14-15: |q|^2 hi/lo
        B[0] = pzl;                            // k8: p_lo.z
        B[1] = pxl; B[2] = pyl; B[3] = pzl;    // k9-11: p_lo
        B[4] = nh;  B[5] = nl;                 // k12-13: |p|^2 hi/lo
        B[6] = one; B[7] = one;                // k14-15: 1.0
    }

    uint4 av, bv;
    av.x = (unsigned int)A[0] | ((unsigned int)A[1] << 16);
    av.y = (unsigned int)A[2] | ((unsigned int)A[3] << 16);
    av.z = (unsigned int)A[4] | ((unsigned int)A[5] << 16);
    av.w = (unsigned int)A[6] | ((unsigned int)A[7] << 16);
    bv.x = (unsigned int)B[0] | ((unsigned int)B[1] << 16);
    bv.y = (unsigned int)B[2] | ((unsigned int)B[3] << 16);
    bv.z = (unsigned int)B[4] | ((unsigned int)B[5] << 16);
    bv.w = (unsigned int)B[6] | ((unsigned int)B[7] << 16);
    Afr[t] = av;
    Bfr[t] = bv;
}

__global__ __launch_bounds__(THREADS, 2)
void chamfer_mfma(const uint4* __restrict__ Afr, const uint4* __restrict__ Bfr,
                  float* __restrict__ out)
{
    __shared__ uint4 Blds[CHUNK * 64];    // 32 KB: one chunk of B fragments

    const int blk = blockIdx.x;           // 0..511
    const int dir = blk >> 8;             // 0: set1 rows, 1: set2 rows
    const int b   = (blk >> 5) & 7;       // batch
    const int rg  = blk & 31;             // row-tile group (4 strips)

    const int t = threadIdx.x;
    const int l = t & 63;
    const int w = t >> 6;                 // wave 0..3 -> row-tile rg*4+w

    const uint4* __restrict__ Abase =
        Afr + ((size_t)((dir * BATCH + b) * TILES + rg * NW + w)) * 64;
    const uint4* __restrict__ Bbase =
        Bfr + ((size_t)(((dir ^ 1) * BATCH + b) * TILES)) * 64;

    const bf16x8 afr = __builtin_bit_cast(bf16x8, Abase[l]);
    const f32x16 zero = {};

    float rmin[16];
    #pragma unroll
    for (int i = 0; i < 16; ++i) rmin[i] = FLT_MAX;

    // stage chunk 0 (256 threads x 8 uint4 = 32 KB)
    #pragma unroll
    for (int i = 0; i < 8; ++i)
        Blds[t + i * THREADS] = Bbase[t + i * THREADS];
    __syncthreads();

    uint4 pf[8];
    for (int c = 0; c < NCHUNK; ++c) {
        if (c + 1 < NCHUNK) {             // prefetch next chunk into registers
            const uint4* __restrict__ src = Bbase + (c + 1) * CHUNK * 64;
            #pragma unroll
            for (int i = 0; i < 8; ++i)
                pf[i] = src[t + i * THREADS];
        }

        #pragma unroll 2
        for (int tt = 0; tt < CHUNK; ++tt) {
            const bf16x8 bfr = __builtin_bit_cast(bf16x8, Blds[tt * 64 + l]);
            const f32x16 acc =
                __builtin_amdgcn_mfma_f32_32x32x16_bf16(afr, bfr, zero, 0, 0, 0);
            #pragma unroll
            for (int i = 0; i < 16; ++i)
                rmin[i] = fminf(rmin[i], acc[i]);
        }

        if (c + 1 < NCHUNK) {
            __syncthreads();              // everyone done reading chunk c
            #pragma unroll
            for (int i = 0; i < 8; ++i)
                Blds[t + i * THREADS] = pf[i];
            __syncthreads();
        }
    }

    // butterfly min over the 32 columns (lanes sharing lane>>5 hold same rows)
    #pragma unroll
    for (int i = 0; i < 16; ++i) {
        float v = rmin[i];
        v = fminf(v, __shfl_xor(v, 1));
        v = fminf(v, __shfl_xor(v, 2));
        v = fminf(v, __shfl_xor(v, 4));
        v = fminf(v, __shfl_xor(v, 8));
        v = fminf(v, __shfl_xor(v, 16));
        rmin[i] = v;                      // row-min for row(i, lane>>5), dup x32
    }

    // sum sqrt over this half's 16 rows, then add the other half's sum
    float s = 0.0f;
    #pragma unroll
    for (int i = 0; i < 16; ++i)
        s += sqrtf(fmaxf(rmin[i], 0.0f));
    s += __shfl_xor(s, 32);               // all 32 rows of the strip

    if (l == 0)
        atomicAdd(out, s * (1.0f / 134217728.0f));   // 2^-27
}

extern "C" void kernel_launch(void* const* d_in, const int* in_sizes, int n_in,
                              void* d_out, int out_size, void* d_ws, size_t ws_size,
                              hipStream_t stream) {
    const float* s1 = (const float*)d_in[0];
    const float* s2 = (const float*)d_in[1];
    float* out = (float*)d_out;
    uint4* Afr = (uint4*)d_ws;
    uint4* Bfr = Afr + FRAGS_PER_SET_PAIR;

    hipMemsetAsync(out, 0, sizeof(float), stream);
    pack_frags<<<dim3(512), dim3(256), 0, stream>>>(s1, s2, Afr, Bfr);
    chamfer_mfma<<<dim3(512), dim3(THREADS), 0, stream>>>(Afr, Bfr, out);
}

// Round 7
// 85.023 us; speedup vs baseline: 1.2450x; 1.2450x over previous
//
#include <hip/hip_runtime.h>
#include <math.h>
#include <float.h>

// ChamferLoss via MFMA: set1/set2 [8, 4096, 3] fp32 -> scalar
//
// d^2[m][n] = |q_m|^2 + |p_n|^2 - 2 q_m.p_n as ONE mfma_f32_32x32x16_bf16 per
// 32x32 tile (hi/lo bf16 split, |p|^2 / |q|^2 folded into k12-15 rank-1 terms;
// absmax 0.0 verified in R6). R7: 1024 slim blocks (4/CU, 50% occ), column
// dimension split in half per block, partial row-mins combined via global
// atomicMin on d^2 bits, separate finish kernel for sqrt+sum.

#define BATCH   8
#define NPTS    4096
#define NSET    (BATCH * NPTS)
#define TILES   (NPTS / 32)      // 128 col-tiles per (dir,b)
#define THREADS 256
#define CHUNK   32               // B-tiles per LDS chunk (32 KB)
#define NCHUNK  2                // 2 chunks = 64 tiles = this block's col-half

typedef __bf16 bf16x8 __attribute__((ext_vector_type(8)));
typedef float  f32x16 __attribute__((ext_vector_type(16)));

static __device__ __forceinline__ unsigned short f2bf(float x) {
    unsigned int u = __float_as_uint(x);
    u += 0x7FFFu + ((u >> 16) & 1u);           // round-to-nearest-even
    return (unsigned short)(u >> 16);
}
static __device__ __forceinline__ float bf2f(unsigned short b) {
    return __uint_as_float(((unsigned int)b) << 16);
}

// ws layout (uint4 units): Afr[131072] | Bfr[131072] ; then qmin[65536] uints
#define FRAGS_PER_SET_PAIR (2 * BATCH * TILES * 64)

__global__ __launch_bounds__(256)
void pack_frags(const float* __restrict__ s1, const float* __restrict__ s2,
                uint4* __restrict__ Afr, uint4* __restrict__ Bfr,
                unsigned int* __restrict__ qmin)
{
    const int t    = blockIdx.x * 256 + threadIdx.x;   // 0..131071
    const int l    = t & 63;
    const int tile = (t >> 6) & (TILES - 1);
    const int b    = (t >> 13) & 7;
    const int set  = t >> 16;

    if (t < 2 * NSET) qmin[t] = 0x7F800000u;   // +inf bits

    const float* __restrict__ src = set ? s2 : s1;
    const int pidx = b * NPTS + tile * 32 + (l & 31);
    const float x = src[3 * pidx + 0];
    const float y = src[3 * pidx + 1];
    const float z = src[3 * pidx + 2];

    const float cx = -2.0f * x, cy = -2.0f * y, cz = -2.0f * z;
    const unsigned short cxh = f2bf(cx), cyh = f2bf(cy), czh = f2bf(cz);
    const unsigned short cxl = f2bf(cx - bf2f(cxh));
    const unsigned short cyl = f2bf(cy - bf2f(cyh));
    const unsigned short czl = f2bf(cz - bf2f(czh));
    const unsigned short pxh = f2bf(x), pyh = f2bf(y), pzh = f2bf(z);
    const unsigned short pxl = f2bf(x - bf2f(pxh));
    const unsigned short pyl = f2bf(y - bf2f(pyh));
    const unsigned short pzl = f2bf(z - bf2f(pzh));
    const float n2 = fmaf(x, x, fmaf(y, y, z * z));
    const unsigned short nh = f2bf(n2), nl = f2bf(n2 - bf2f(nh));
    const unsigned short one = 0x3F80;

    unsigned short A[8], B[8];
    if (l < 32) {            // j0..7 <-> k0..7
        A[0] = cxh; A[1] = cyh; A[2] = czh;    // k0-2:  -2q_hi
        A[3] = cxl; A[4] = cyl; A[5] = czl;    // k3-5:  -2q_lo
        A[6] = cxh; A[7] = cyh;                // k6-7:  -2q_hi.xy
        B[0] = pxh; B[1] = pyh; B[2] = pzh;    // k0-2:  p_hi
        B[3] = pxh; B[4] = pyh; B[5] = pzh;    // k3-5:  p_hi
        B[6] = pxl; B[7] = pyl;                // k6-7:  p_lo.xy
    } else {                 // j0..7 <-> k8..15
        A[0] = czh;                            // k8:    -2q_hi.z
        A[1] = cxl; A[2] = cyl; A[3] = czl;    // k9-11: -2q_lo
        A[4] = one; A[5] = one;                // k12-13: 1.0
        A[6] = nh;  A[7] = nl;                 // k14-15: |q|^2 hi/lo
        B[0] = pzl;                            // k8:    p_lo.z
        B[1] = pxl; B[2] = pyl; B[3] = pzl;    // k9-11: p_lo
        B[4] = nh;  B[5] = nl;                 // k12-13: |p|^2 hi/lo
        B[6] = one; B[7] = one;                // k14-15: 1.0
    }

    uint4 av, bv;
    av.x = (unsigned int)A[0] | ((unsigned int)A[1] << 16);
    av.y = (unsigned int)A[2] | ((unsigned int)A[3] << 16);
    av.z = (unsigned int)A[4] | ((unsigned int)A[5] << 16);
    av.w = (unsigned int)A[6] | ((unsigned int)A[7] << 16);
    bv.x = (unsigned int)B[0] | ((unsigned int)B[1] << 16);
    bv.y = (unsigned int)B[2] | ((unsigned int)B[3] << 16);
    bv.z = (unsigned int)B[4] | ((unsigned int)B[5] << 16);
    bv.w = (unsigned int)B[6] | ((unsigned int)B[7] << 16);
    Afr[t] = av;
    Bfr[t] = bv;
}

__global__ __launch_bounds__(THREADS, 4)
void chamfer_mfma(const uint4* __restrict__ Afr, const uint4* __restrict__ Bfr,
                  unsigned int* __restrict__ qmin)
{
    __shared__ uint4 Blds[CHUNK * 64];    // 32 KB: one chunk of B fragments

    // 1024 blocks: dir(2) x batch(8) x rowgroup(32) x colhalf(2)
    const int blk = blockIdx.x;
    const int dir = blk >> 9;
    const int b   = (blk >> 6) & 7;
    const int rg  = (blk >> 1) & 31;      // 32 rowgroups of 4 row-tiles
    const int ch  = blk & 1;              // column half (64 tiles)

    const int t = threadIdx.x;
    const int l = t & 63;
    const int w = t >> 6;                 // wave 0..3 -> row-tile rg*4+w

    const int rowtile = rg * 4 + w;
    const uint4* __restrict__ Abase =
        Afr + ((size_t)((dir * BATCH + b) * TILES + rowtile)) * 64;
    const uint4* __restrict__ Bbase =
        Bfr + ((size_t)(((dir ^ 1) * BATCH + b) * TILES + ch * 64)) * 64;

    const bf16x8 afr = __builtin_bit_cast(bf16x8, Abase[l]);
    const f32x16 zero = {};

    float rmin[16];
    #pragma unroll
    for (int i = 0; i < 16; ++i) rmin[i] = FLT_MAX;

    // stage chunk 0 (256 threads x 8 uint4 = 32 KB)
    #pragma unroll
    for (int i = 0; i < 8; ++i)
        Blds[t + i * THREADS] = Bbase[t + i * THREADS];
    __syncthreads();

    uint4 pf[8];
    for (int c = 0; c < NCHUNK; ++c) {
        if (c + 1 < NCHUNK) {             // prefetch next chunk into registers
            const uint4* __restrict__ src = Bbase + (c + 1) * CHUNK * 64;
            #pragma unroll
            for (int i = 0; i < 8; ++i)
                pf[i] = src[t + i * THREADS];
        }

        #pragma unroll 4
        for (int tt = 0; tt < CHUNK; ++tt) {
            const bf16x8 bfr = __builtin_bit_cast(bf16x8, Blds[tt * 64 + l]);
            const f32x16 acc =
                __builtin_amdgcn_mfma_f32_32x32x16_bf16(afr, bfr, zero, 0, 0, 0);
            #pragma unroll
            for (int i = 0; i < 16; ++i)
                rmin[i] = fminf(rmin[i], acc[i]);
        }

        if (c + 1 < NCHUNK) {
            __syncthreads();
            #pragma unroll
            for (int i = 0; i < 8; ++i)
                Blds[t + i * THREADS] = pf[i];
            __syncthreads();
        }
    }

    // butterfly min over this half-wave's 32 columns (stays within 32 lanes)
    #pragma unroll
    for (int i = 0; i < 16; ++i) {
        float v = rmin[i];
        v = fminf(v, __shfl_xor(v, 1));
        v = fminf(v, __shfl_xor(v, 2));
        v = fminf(v, __shfl_xor(v, 4));
        v = fminf(v, __shfl_xor(v, 8));
        v = fminf(v, __shfl_xor(v, 16));
        rmin[i] = v;                      // partial row-min, dup x32
    }

    // lanes 0..15 of each 32-half emit one atomicMin per row
    const int half = l >> 5;              // lane>>5 term of the C/D row mapping
    const int i    = l & 31;              // 0..15 used
    if (i < 16) {
        const int row = (i & 3) + 8 * (i >> 2) + 4 * half;
        const float d2 = fmaxf(rmin[i], 0.0f);
        const int gq = (dir * BATCH + b) * NPTS + rowtile * 32 + row;
        atomicMin(&qmin[gq], __float_as_uint(d2));
    }
}

__global__ __launch_bounds__(256)
void finish(const unsigned int* __restrict__ qmin, float* __restrict__ out)
{
    const int t = blockIdx.x * 256 + threadIdx.x;         // 0..16383
    const uint4 v = ((const uint4*)qmin)[t];
    float s = sqrtf(__uint_as_float(v.x)) + sqrtf(__uint_as_float(v.y))
            + sqrtf(__uint_as_float(v.z)) + sqrtf(__uint_as_float(v.w));
    #pragma unroll
    for (int off = 32; off > 0; off >>= 1)
        s += __shfl_down(s, off);
    if ((threadIdx.x & 63) == 0)
        atomicAdd(out, s * (1.0f / 134217728.0f));        // 2^-27
}

extern "C" void kernel_launch(void* const* d_in, const int* in_sizes, int n_in,
                              void* d_out, int out_size, void* d_ws, size_t ws_size,
                              hipStream_t stream) {
    const float* s1 = (const float*)d_in[0];
    const float* s2 = (const float*)d_in[1];
    float* out = (float*)d_out;
    uint4* Afr = (uint4*)d_ws;
    uint4* Bfr = Afr + FRAGS_PER_SET_PAIR;
    unsigned int* qmin = (unsigned int*)(Bfr + FRAGS_PER_SET_PAIR);

    hipMemsetAsync(out, 0, sizeof(float), stream);
    pack_frags<<<dim3(512),  dim3(256), 0, stream>>>(s1, s2, Afr, Bfr, qmin);
    chamfer_mfma<<<dim3(1024), dim3(THREADS), 0, stream>>>(Afr, Bfr, qmin);
    finish<<<dim3(64),       dim3(256), 0, stream>>>(qmin, out);
}